// Round 8
// baseline (114.440 us; speedup 1.0000x reference)
//
#include <hip/hip_runtime.h>

// One-pole IIR over time, B channels x T samples.
//   out_t = b0*x_t + s_t
//   s_{t+1} = b1*x_t + a1c*out_t = a1c*s_t + c*x_t,  c = b1 + a1c*b0
//
// r8: EXACT wave-parallel scan, no LDS, single dispatch.
// Wave = one channel row. Per 256-sample segment: lane l holds samples
// 4l..4l+3 (float4 -> every global load/store instruction is one contiguous
// 1KB burst, the same shape as the 6.9 TB/s fill kernel). In-lane 3-FMA
// prefix, 6-step shuffle (Hillis-Steele) scan with per-lane masked a^(4k)
// multipliers (no divergence), exclusive fixup, 8 output FMAs. Segment carry
// is exact: s0' = a^256*s0 + S[63]. Valid for ALL a1 (scan reassociation
// only) -> no warm-up approximation, no mode kernels, no fallback launches.
// Ring-4 register prefetch -> counted vmcnt, ~4-segment issue->use distance.
// Fallback (T % 1024 != 0, host-decided): serial per-channel kernel.

__device__ __forceinline__ float clamp_a1f(float a) {
    return fminf(fmaxf(a, -1.0f), 1.0f);
}

__global__ __launch_bounds__(256)
void k_wavescan(const float* __restrict__ x,
                const float* __restrict__ state,
                const float* __restrict__ b0p,
                const float* __restrict__ b1p,
                const float* __restrict__ a1p,
                float* __restrict__ out,           // [B][T]
                float* __restrict__ final_state,   // [B]
                int B, int T) {
    const int w    = threadIdx.x >> 6;
    const int lane = threadIdx.x & 63;
    const int b    = (blockIdx.x << 2) + w;
    if (b >= B) return;

    const float a  = clamp_a1f(a1p[0]);
    const float b0 = b0p[0];
    const float b1 = b1p[0];
    const float c  = fmaf(a, b0, b1);

    // powers of a (even exponents -> non-negative regardless of sign of a)
    const float a2 = a * a,  a4 = a2 * a2,  a8 = a4 * a4,  a16 = a8 * a8;
    const float a32 = a16 * a16, a64 = a32 * a32, a128 = a64 * a64, a256 = a128 * a128;

    // per-lane masked scan multipliers (0 where the shuffle would wrap)
    const float m1  = (lane >= 1)  ? a4   : 0.0f;
    const float m2  = (lane >= 2)  ? a8   : 0.0f;
    const float m4  = (lane >= 4)  ? a16  : 0.0f;
    const float m8  = (lane >= 8)  ? a32  : 0.0f;
    const float m16 = (lane >= 16) ? a64  : 0.0f;
    const float m32 = (lane >= 32) ? a128 : 0.0f;
    const float mE  = (lane == 0)  ? 0.0f : 1.0f;
    const float pla = powf(fabsf(a), (float)(4 * lane));  // a^(4*lane), exponent even

    const float4* xrow = (const float4*)(x   + (size_t)b * T);
    float4*       orow = (float4*)      (out + (size_t)b * T);
    const int nit = T >> 8;  // 256-sample segments (T % 1024 == 0 guaranteed)

    float s0 = state[b];  // wave-uniform carry

    // ring-4 prefetch
    float4 r0 = xrow[0 * 64 + lane];
    float4 r1 = xrow[1 * 64 + lane];
    float4 r2 = xrow[2 * 64 + lane];
    float4 r3 = xrow[3 * 64 + lane];

#define STEP(R, IT)                                                             \
    {                                                                           \
        float z0 = c * R.x, z1 = c * R.y, z2 = c * R.z, z3 = c * R.w;           \
        float p = z0;                                                           \
        p = fmaf(a, p, z1);                                                     \
        p = fmaf(a, p, z2);                                                     \
        p = fmaf(a, p, z3);                                                     \
        float S = p;                                                            \
        S = fmaf(m1,  __shfl_up(S, 1),  S);                                     \
        S = fmaf(m2,  __shfl_up(S, 2),  S);                                     \
        S = fmaf(m4,  __shfl_up(S, 4),  S);                                     \
        S = fmaf(m8,  __shfl_up(S, 8),  S);                                     \
        S = fmaf(m16, __shfl_up(S, 16), S);                                     \
        S = fmaf(m32, __shfl_up(S, 32), S);                                     \
        float E  = __shfl_up(S, 1) * mE;  /* exclusive: segment-local u(4l) */  \
        float sb = fmaf(pla, s0, E);      /* state before lane's sample 0 */    \
        float4 o;                                                               \
        o.x = fmaf(b0, R.x, sb); sb = fmaf(a, sb, z0);                          \
        o.y = fmaf(b0, R.y, sb); sb = fmaf(a, sb, z1);                          \
        o.z = fmaf(b0, R.z, sb); sb = fmaf(a, sb, z2);                          \
        o.w = fmaf(b0, R.w, sb); sb = fmaf(a, sb, z3);                          \
        orow[(IT) * 64 + lane] = o;                                             \
        s0 = fmaf(a256, s0, __shfl(S, 63));  /* exact segment carry */          \
    }

    for (int it = 0; it < nit; it += 4) {
        STEP(r0, it + 0) if (it + 4 < nit) r0 = xrow[(it + 4) * 64 + lane];
        STEP(r1, it + 1) if (it + 5 < nit) r1 = xrow[(it + 5) * 64 + lane];
        STEP(r2, it + 2) if (it + 6 < nit) r2 = xrow[(it + 6) * 64 + lane];
        STEP(r3, it + 3) if (it + 7 < nit) r3 = xrow[(it + 7) * 64 + lane];
    }
#undef STEP

    if (lane == 0) final_state[b] = s0;
}

// correctness-only fallback for shapes the wave-scan doesn't cover
__global__ void k_serial(const float* __restrict__ x,
                         const float* __restrict__ state,
                         const float* __restrict__ b0p,
                         const float* __restrict__ b1p,
                         const float* __restrict__ a1p,
                         float* __restrict__ out,
                         float* __restrict__ final_state,
                         int B, int T) {
    int b = blockIdx.x * blockDim.x + threadIdx.x;
    if (b >= B) return;
    float a  = clamp_a1f(a1p[0]);
    float b0 = b0p[0];
    float b1 = b1p[0];
    float s = state[b];
    const float* xr = x + (size_t)b * T;
    float* orr = out + (size_t)b * T;
    for (int t = 0; t < T; ++t) {
        float v = xr[t];
        float o = fmaf(b0, v, s);
        s = fmaf(b1, v, a * o);
        orr[t] = o;
    }
    final_state[b] = s;
}

extern "C" void kernel_launch(void* const* d_in, const int* in_sizes, int n_in,
                              void* d_out, int out_size, void* d_ws, size_t ws_size,
                              hipStream_t stream) {
    const float* x     = (const float*)d_in[0];
    const float* state = (const float*)d_in[1];
    const float* b0p   = (const float*)d_in[2];
    const float* b1p   = (const float*)d_in[3];
    const float* a1p   = (const float*)d_in[4];

    int B = in_sizes[1];                 // 4096
    int T = in_sizes[0] / B;             // 16384

    float* out         = (float*)d_out;                   // [B][T]
    float* final_state = (float*)d_out + (size_t)B * T;   // [B]

    if (T >= 1024 && (T % 1024) == 0) {
        // one wave per channel row; 4 rows per 256-thread block
        int grid = (B + 3) / 4;
        k_wavescan<<<grid, 256, 0, stream>>>(x, state, b0p, b1p, a1p,
                                             out, final_state, B, T);
    } else {
        int grid = (B + 255) / 256;
        k_serial<<<grid, 256, 0, stream>>>(x, state, b0p, b1p, a1p,
                                           out, final_state, B, T);
    }
}

// Round 9
// 88.321 us; speedup vs baseline: 1.2957x; 1.2957x over previous
//
#include <hip/hip_runtime.h>

// One-pole IIR over time, B channels x T samples.
//   out_t = b0*x_t + s_t
//   s_{t+1} = b1*x_t + a1c*out_t = a1c*s_t + c*x_t,  c = b1 + a1c*b0
//
// r9: EXACT wave-parallel scan, no LDS, single dispatch, 4-segment ILP.
// Wave = one channel row. Segment = 256 samples; lane l holds samples
// 4l..4l+3 (every global load/store is one contiguous 1KB burst).
// Groups of 4 segments: phase 1 = 4 INDEPENDENT {local 3-FMA prefix +
// 6-step masked shuffle scan} chains (ILP hides DS latency — r8's serial
// per-segment chain was the bottleneck); phase 2 = 4 serial carry FMAs
// (s' = a^256*s + tail); phase 3 = 4 independent output blocks (NT stores).
// Ring-8 register prefetch (2 groups) -> counted vmcnt, ~1-group distance.
// Exact for ALL a1 (scan reassociation only). Fallback: serial kernel.

typedef float f32x4 __attribute__((ext_vector_type(4)));

__device__ __forceinline__ float clamp_a1f(float a) {
    return fminf(fmaxf(a, -1.0f), 1.0f);
}

__device__ __forceinline__ float loc_prefix(const float4 R, float a, float c) {
    float p = c * R.x;
    p = fmaf(a, p, c * R.y);
    p = fmaf(a, p, c * R.z);
    p = fmaf(a, p, c * R.w);
    return p;
}

__device__ __forceinline__ float wscan(float p, float m1, float m2, float m4,
                                       float m8, float m16, float m32) {
    float S = p;
    S = fmaf(m1,  __shfl_up(S, 1),  S);
    S = fmaf(m2,  __shfl_up(S, 2),  S);
    S = fmaf(m4,  __shfl_up(S, 4),  S);
    S = fmaf(m8,  __shfl_up(S, 8),  S);
    S = fmaf(m16, __shfl_up(S, 16), S);
    S = fmaf(m32, __shfl_up(S, 32), S);
    return S;
}

__device__ __forceinline__ void emit_seg(const float4 R, float sbase, float E,
                                         float pla, float a, float b0, float c,
                                         float4* orow, int it, int lane) {
    float sb = fmaf(pla, sbase, E);  // state before this lane's sample 0
    f32x4 o;
    o.x = fmaf(b0, R.x, sb); sb = fmaf(a, sb, c * R.x);
    o.y = fmaf(b0, R.y, sb); sb = fmaf(a, sb, c * R.y);
    o.z = fmaf(b0, R.z, sb); sb = fmaf(a, sb, c * R.z);
    o.w = fmaf(b0, R.w, sb);
    __builtin_nontemporal_store(o, (f32x4*)(orow + it * 64 + lane));
}

__global__ __launch_bounds__(256)
void k_wavescan(const float* __restrict__ x,
                const float* __restrict__ state,
                const float* __restrict__ b0p,
                const float* __restrict__ b1p,
                const float* __restrict__ a1p,
                float* __restrict__ out,           // [B][T]
                float* __restrict__ final_state,   // [B]
                int B, int T) {
    const int w    = threadIdx.x >> 6;
    const int lane = threadIdx.x & 63;
    const int b    = (blockIdx.x << 2) + w;
    if (b >= B) return;

    const float a  = clamp_a1f(a1p[0]);
    const float b0 = b0p[0];
    const float b1 = b1p[0];
    const float c  = fmaf(a, b0, b1);

    // powers of a (even exponents -> sign-safe)
    const float a2 = a * a,  a4 = a2 * a2,  a8 = a4 * a4,  a16 = a8 * a8;
    const float a32 = a16 * a16, a64 = a32 * a32, a128 = a64 * a64, a256 = a128 * a128;

    // per-lane masked scan multipliers (0 where the shuffle would wrap)
    const float m1  = (lane >= 1)  ? a4   : 0.0f;
    const float m2  = (lane >= 2)  ? a8   : 0.0f;
    const float m4  = (lane >= 4)  ? a16  : 0.0f;
    const float m8  = (lane >= 8)  ? a32  : 0.0f;
    const float m16 = (lane >= 16) ? a64  : 0.0f;
    const float m32 = (lane >= 32) ? a128 : 0.0f;
    const float mE  = (lane == 0)  ? 0.0f : 1.0f;
    const float pla = powf(fabsf(a), (float)(4 * lane));  // a^(4*lane), even exp

    const float4* xrow = (const float4*)(x   + (size_t)b * T);
    float4*       orow = (float4*)      (out + (size_t)b * T);
    const int nit = T >> 8;  // 256-sample segments; nit % 8 == 0 (host guard)

    float s0 = state[b];  // wave-uniform carry

    // ring-8 prefetch (2 groups of 4 segments)
    float4 rA0 = xrow[0 * 64 + lane], rA1 = xrow[1 * 64 + lane];
    float4 rA2 = xrow[2 * 64 + lane], rA3 = xrow[3 * 64 + lane];
    float4 rB0 = xrow[4 * 64 + lane], rB1 = xrow[5 * 64 + lane];
    float4 rB2 = xrow[6 * 64 + lane], rB3 = xrow[7 * 64 + lane];

#define GROUP(R0, R1, R2, R3, IT)                                               \
    {                                                                           \
        /* phase 1: 4 independent prefix+scan chains (ILP on DS latency) */     \
        float p0 = loc_prefix(R0, a, c);                                        \
        float p1 = loc_prefix(R1, a, c);                                        \
        float p2 = loc_prefix(R2, a, c);                                        \
        float p3 = loc_prefix(R3, a, c);                                        \
        float S0 = wscan(p0, m1, m2, m4, m8, m16, m32);                         \
        float S1 = wscan(p1, m1, m2, m4, m8, m16, m32);                         \
        float S2 = wscan(p2, m1, m2, m4, m8, m16, m32);                         \
        float S3 = wscan(p3, m1, m2, m4, m8, m16, m32);                         \
        float E0 = __shfl_up(S0, 1) * mE, t0_ = __shfl(S0, 63);                 \
        float E1 = __shfl_up(S1, 1) * mE, t1_ = __shfl(S1, 63);                 \
        float E2 = __shfl_up(S2, 1) * mE, t2_ = __shfl(S2, 63);                 \
        float E3 = __shfl_up(S3, 1) * mE, t3_ = __shfl(S3, 63);                 \
        /* phase 2: serial carry, 1 FMA per segment */                          \
        float sA = s0;                                                          \
        float sB = fmaf(a256, sA, t0_);                                         \
        float sC = fmaf(a256, sB, t1_);                                         \
        float sD = fmaf(a256, sC, t2_);                                         \
        s0       = fmaf(a256, sD, t3_);                                         \
        /* phase 3: 4 independent output blocks */                              \
        emit_seg(R0, sA, E0, pla, a, b0, c, orow, (IT) + 0, lane);              \
        emit_seg(R1, sB, E1, pla, a, b0, c, orow, (IT) + 1, lane);              \
        emit_seg(R2, sC, E2, pla, a, b0, c, orow, (IT) + 2, lane);              \
        emit_seg(R3, sD, E3, pla, a, b0, c, orow, (IT) + 3, lane);              \
    }

    for (int it = 0; it < nit; it += 8) {
        GROUP(rA0, rA1, rA2, rA3, it)
        if (it + 8 < nit) {  // prefetch next A-group (uniform branch)
            rA0 = xrow[(it + 8)  * 64 + lane];
            rA1 = xrow[(it + 9)  * 64 + lane];
            rA2 = xrow[(it + 10) * 64 + lane];
            rA3 = xrow[(it + 11) * 64 + lane];
        }
        GROUP(rB0, rB1, rB2, rB3, it + 4)
        if (it + 12 < nit) {  // prefetch next B-group
            rB0 = xrow[(it + 12) * 64 + lane];
            rB1 = xrow[(it + 13) * 64 + lane];
            rB2 = xrow[(it + 14) * 64 + lane];
            rB3 = xrow[(it + 15) * 64 + lane];
        }
    }
#undef GROUP

    if (lane == 0) final_state[b] = s0;
}

// correctness-only fallback for shapes the wave-scan doesn't cover
__global__ void k_serial(const float* __restrict__ x,
                         const float* __restrict__ state,
                         const float* __restrict__ b0p,
                         const float* __restrict__ b1p,
                         const float* __restrict__ a1p,
                         float* __restrict__ out,
                         float* __restrict__ final_state,
                         int B, int T) {
    int b = blockIdx.x * blockDim.x + threadIdx.x;
    if (b >= B) return;
    float a  = clamp_a1f(a1p[0]);
    float b0 = b0p[0];
    float b1 = b1p[0];
    float s = state[b];
    const float* xr = x + (size_t)b * T;
    float* orr = out + (size_t)b * T;
    for (int t = 0; t < T; ++t) {
        float v = xr[t];
        float o = fmaf(b0, v, s);
        s = fmaf(b1, v, a * o);
        orr[t] = o;
    }
    final_state[b] = s;
}

extern "C" void kernel_launch(void* const* d_in, const int* in_sizes, int n_in,
                              void* d_out, int out_size, void* d_ws, size_t ws_size,
                              hipStream_t stream) {
    const float* x     = (const float*)d_in[0];
    const float* state = (const float*)d_in[1];
    const float* b0p   = (const float*)d_in[2];
    const float* b1p   = (const float*)d_in[3];
    const float* a1p   = (const float*)d_in[4];

    int B = in_sizes[1];                 // 4096
    int T = in_sizes[0] / B;             // 16384

    float* out         = (float*)d_out;                   // [B][T]
    float* final_state = (float*)d_out + (size_t)B * T;   // [B]

    if (T >= 2048 && (T % 2048) == 0) {
        // one wave per channel row; 4 rows per 256-thread block
        int grid = (B + 3) / 4;
        k_wavescan<<<grid, 256, 0, stream>>>(x, state, b0p, b1p, a1p,
                                             out, final_state, B, T);
    } else {
        int grid = (B + 255) / 256;
        k_serial<<<grid, 256, 0, stream>>>(x, state, b0p, b1p, a1p,
                                           out, final_state, B, T);
    }
}